// Round 10
// baseline (627.697 us; speedup 1.0000x reference)
//
#include <hip/hip_runtime.h>

#define ENC_T 20
#define DEC_T 30

typedef _Float16 f16x8 __attribute__((ext_vector_type(8)));
typedef _Float16 f16x2 __attribute__((ext_vector_type(2)));
typedef float f32x16 __attribute__((ext_vector_type(16)));
typedef unsigned u32x4 __attribute__((ext_vector_type(4)));

// LDS (bytes):  W 32KB | WX 8KB | EMB 4KB  = 44KB. No h buffers (h lives in regs).
//   WOFF:  [256 n][64 k] f16 swizzled byte = n*128 + ((2k)^((n&7)<<4)). A-operand.
//          enc: Whh_enc; dec: Wih_dec+Whh_dec.
//   WXOFF: [256 n][16 k] f16 linear rows (32B). enc: k0=w0,k1=w1,k2=b_tot.
//          dec: k0=b_tot, rest 0 (bias via ones-MFMA).
//   EMBOFF:[32 n][64 k] f16 swizzled like W. rows 0,1 = Wemb, rest 0.
#define WOFF   0
#define WXOFF  32768
#define EMBOFF 40960
#define LDS_BYTES 45056

__device__ __forceinline__ float sigf(float x) {
    return __builtin_amdgcn_rcpf(1.0f + __builtin_amdgcn_exp2f(-1.442695040f * x));
}
__device__ __forceinline__ float tanhf_n(float x) {
    return __builtin_fmaf(2.0f, __builtin_amdgcn_rcpf(1.0f + __builtin_amdgcn_exp2f(-2.885390081f * x)), -1.0f);
}
// RTNE f16 pack (R10): cvt_pkrtz is round-toward-zero = BIASED; over the
// 50-step recurrence the coherent bias amplifies (R9's 1.17e-2). RTNE
// scalar casts give unbiased random-walk error (R7 measured 2.44e-4).
__device__ __forceinline__ unsigned pkrtne(float a, float b) {
    f16x2 v; v[0] = (_Float16)a; v[1] = (_Float16)b;
    return __builtin_bit_cast(unsigned, v);
}

// Transposed-GEMM design: C[row=gate, col=batch]; lane owns batch col cl.
// Next-step B-frags (h) assembled IN REGISTERS. Cross-half exchange via
// __shfl_xor(.,32) + select (R10: replaces permlane asm — semantics
// unambiguous by construction):
//   hi=0 lane frag = [own pa0, own pa1, partner pa0, partner pa1]
//   hi=1 lane frag = [partner pb0, partner pb1, own pb0, own pb1]
// where pa = pk(hv[0..3]) (j offs {0..3}+4hi), pb = pk(hv[4..7]) ({8..11}+4hi).
__global__ __launch_bounds__(256, 2)
void lstm_s2s_kernel(const float* __restrict__ xin,
                     const float* __restrict__ Wih_e, const float* __restrict__ Whh_e,
                     const float* __restrict__ bih_e, const float* __restrict__ bhh_e,
                     const float* __restrict__ Wih_d, const float* __restrict__ Whh_d,
                     const float* __restrict__ bih_d, const float* __restrict__ bhh_d,
                     const float* __restrict__ Wemb, const float* __restrict__ bemb,
                     float* __restrict__ out, int B)
{
    __shared__ __align__(16) unsigned char lds[LDS_BYTES];
    const int tid  = threadIdx.x;
    const int wid  = tid >> 6;
    const int lane = tid & 63;
    const int cl   = lane & 31;        // per-lane batch index (C col) / A row n
    const int hi   = lane >> 5;        // k-half select
    const int hi2  = hi ^ (cl & 1);    // bit4 of W-swizzle folded into base
    const int cc2  = (cl >> 1) & 3;    // bits 5-6 of W-swizzle
    const int r0   = blockIdx.x * 128 + wid * 32;

    // ---------------- stage tables (enc W, WX, EMB) ----------------
    for (int i = tid; i < 256 * 64; i += 256) {
        int n = i >> 6, k = i & 63;
        *(_Float16*)(lds + WOFF + n * 128 + ((k * 2) ^ ((n & 7) << 4))) = (_Float16)Whh_e[i];
    }
    {   // WX row n: k0=w0, k1=w1, k2=b_ih+b_hh, k3..15 = 0
        int n = tid;
        float w0 = Wih_e[n * 2 + 0], w1 = Wih_e[n * 2 + 1];
        float bt = bih_e[n] + bhh_e[n];
        _Float16* row = (_Float16*)(lds + WXOFF + n * 32);
        #pragma unroll
        for (int k = 0; k < 16; ++k)
            row[k] = (_Float16)((k == 0) ? w0 : (k == 1) ? w1 : (k == 2) ? bt : 0.0f);
    }
    for (int i = tid; i < 32 * 64; i += 256) {
        int n = i >> 6, k = i & 63;
        float v = (n < 2) ? Wemb[n * 64 + k] : 0.0f;
        *(_Float16*)(lds + EMBOFF + n * 128 + ((k * 2) ^ ((n & 7) << 4))) = (_Float16)v;
    }
    __syncthreads();

    // W A-frag read bases: canonical k-chunk m for every lane (K-pairing!).
    const unsigned rb_w = WOFF + cl * 128 + hi2 * 16;
    unsigned wa[4];
    #pragma unroll
    for (int m = 0; m < 4; ++m) wa[m] = rb_w + (unsigned)((m ^ cc2) << 5);
    const unsigned xb = WXOFF + cl * 32 + hi * 16;   // WX A-frag base (linear rows)

    float c[32];
    #pragma unroll
    for (int i = 0; i < 32; ++i) c[i] = 0.0f;

    f16x8 hB[4];                        // h0 = 0
    #pragma unroll
    for (int m = 0; m < 4; ++m)
        #pragma unroll
        for (int e = 0; e < 8; ++e) hB[m][e] = (_Float16)0.0f;

    f32x16 zz;
    #pragma unroll
    for (int q = 0; q < 16; ++q) zz[q] = 0.0f;

    // x B-frag constants: word1 = [1.0, 0] on hi=0 (bias k-slot), zeros elsewhere
    const unsigned xw1 = hi ? 0u : pkrtne(1.0f, 0.0f);
    const float* xp0 = xin + (size_t)(r0 + cl) * (ENC_T * 2);

    // ---------------- encoder: 20 steps ----------------
    for (int t = 0; t < ENC_T; ++t) {
        float x0 = xp0[t * 2 + 0], x1 = xp0[t * 2 + 1];
        unsigned xw0 = hi ? 0u : pkrtne(x0, x1);
        u32x4 xw; xw[0] = xw0; xw[1] = xw1; xw[2] = 0u; xw[3] = 0u;
        f16x8 xB = __builtin_bit_cast(f16x8, xw);

        f32x16 acc[8];
        #pragma unroll
        for (int t8 = 0; t8 < 8; ++t8) {
            f16x8 wx = *(const f16x8*)(lds + xb + t8 * 1024);   // A: WX tile
            acc[t8] = __builtin_amdgcn_mfma_f32_32x32x16_f16(wx, xB, zz, 0, 0, 0);
        }
        #pragma unroll
        for (int m = 0; m < 4; ++m)
            #pragma unroll
            for (int t8 = 0; t8 < 8; ++t8) {
                f16x8 wb = *(const f16x8*)(lds + wa[m] + t8 * 4096);   // A: W tile
                acc[t8] = __builtin_amdgcn_mfma_f32_32x32x16_f16(wb, hB[m], acc[t8], 0, 0, 0);
            }

        // cell + in-register h-frag rebuild
        #pragma unroll
        for (int js = 0; js < 2; ++js) {
            #pragma unroll
            for (int mu = 0; mu < 2; ++mu) {
                float hv[8];
                #pragma unroll
                for (int q = 0; q < 8; ++q) {
                    int r = mu * 8 + q;
                    float iv = acc[0 + js][r];
                    float fv = acc[2 + js][r];
                    float gv = acc[4 + js][r];
                    float ov = acc[6 + js][r];
                    float cc = c[js * 16 + r];
                    float ct = __builtin_fmaf(sigf(fv), cc, sigf(iv) * tanhf_n(gv));
                    c[js * 16 + r] = ct;
                    hv[q] = sigf(ov) * tanhf_n(ct);
                }
                unsigned pa0 = pkrtne(hv[0], hv[1]), pa1 = pkrtne(hv[2], hv[3]);
                unsigned pb0 = pkrtne(hv[4], hv[5]), pb1 = pkrtne(hv[6], hv[7]);
                unsigned qa0 = (unsigned)__shfl_xor((int)pa0, 32, 64);
                unsigned qa1 = (unsigned)__shfl_xor((int)pa1, 32, 64);
                unsigned qb0 = (unsigned)__shfl_xor((int)pb0, 32, 64);
                unsigned qb1 = (unsigned)__shfl_xor((int)pb1, 32, 64);
                u32x4 w;
                w[0] = hi ? qb0 : pa0;
                w[1] = hi ? qb1 : pa1;
                w[2] = hi ? pb0 : qa0;
                w[3] = hi ? pb1 : qa1;
                hB[js * 2 + mu] = __builtin_bit_cast(f16x8, w);
            }
        }
    }

    // ---------------- restage decoder tables ----------------
    __syncthreads();   // all waves done reading enc W/WX
    for (int i = tid; i < 256 * 64; i += 256) {
        int n = i >> 6, k = i & 63;
        *(_Float16*)(lds + WOFF + n * 128 + ((k * 2) ^ ((n & 7) << 4))) =
            (_Float16)(Wih_d[i] + Whh_d[i]);   // x==h -> combine
    }
    {   // WX row n: k0 = b_tot_dec, rest 0  (bias via ones-MFMA)
        int n = tid;
        float bt = bih_d[n] + bhh_d[n];
        _Float16* row = (_Float16*)(lds + WXOFF + n * 32);
        #pragma unroll
        for (int k = 0; k < 16; ++k)
            row[k] = (_Float16)((k == 0) ? bt : 0.0f);
    }
    const float b0 = bemb[0], b1 = bemb[1];
    // ones B-frag: k0 = 1 on hi=0
    u32x4 ow; ow[0] = hi ? 0u : pkrtne(1.0f, 0.0f); ow[1] = 0u; ow[2] = 0u; ow[3] = 0u;
    const f16x8 oneB = __builtin_bit_cast(f16x8, ow);
    __syncthreads();

    float* outp = out + (size_t)(r0 + cl) * (DEC_T * 2);

    // ---------------- decoder: 30 steps ----------------
    for (int t = 0; t < DEC_T; ++t) {
        f32x16 acc[8];
        #pragma unroll
        for (int t8 = 0; t8 < 8; ++t8) {
            f16x8 wx = *(const f16x8*)(lds + xb + t8 * 1024);   // bias tile
            acc[t8] = __builtin_amdgcn_mfma_f32_32x32x16_f16(wx, oneB, zz, 0, 0, 0);
        }
        #pragma unroll
        for (int m = 0; m < 4; ++m)
            #pragma unroll
            for (int t8 = 0; t8 < 8; ++t8) {
                f16x8 wb = *(const f16x8*)(lds + wa[m] + t8 * 4096);
                acc[t8] = __builtin_amdgcn_mfma_f32_32x32x16_f16(wb, hB[m], acc[t8], 0, 0, 0);
            }

        #pragma unroll
        for (int js = 0; js < 2; ++js) {
            #pragma unroll
            for (int mu = 0; mu < 2; ++mu) {
                float hv[8];
                #pragma unroll
                for (int q = 0; q < 8; ++q) {
                    int r = mu * 8 + q;
                    float iv = acc[0 + js][r];
                    float fv = acc[2 + js][r];
                    float gv = acc[4 + js][r];
                    float ov = acc[6 + js][r];
                    float cc = c[js * 16 + r];
                    float ct = __builtin_fmaf(sigf(fv), cc, sigf(iv) * tanhf_n(gv));
                    c[js * 16 + r] = ct;
                    hv[q] = sigf(ov) * tanhf_n(ct);
                }
                unsigned pa0 = pkrtne(hv[0], hv[1]), pa1 = pkrtne(hv[2], hv[3]);
                unsigned pb0 = pkrtne(hv[4], hv[5]), pb1 = pkrtne(hv[6], hv[7]);
                unsigned qa0 = (unsigned)__shfl_xor((int)pa0, 32, 64);
                unsigned qa1 = (unsigned)__shfl_xor((int)pa1, 32, 64);
                unsigned qb0 = (unsigned)__shfl_xor((int)pb0, 32, 64);
                unsigned qb1 = (unsigned)__shfl_xor((int)pb1, 32, 64);
                u32x4 w;
                w[0] = hi ? qb0 : pa0;
                w[1] = hi ? qb1 : pa1;
                w[2] = hi ? pb0 : qa0;
                w[3] = hi ? pb1 : qa1;
                hB[js * 2 + mu] = __builtin_bit_cast(f16x8, w);
            }
        }

        // pred = Wemb @ h_t  (A: EMB tiles via wa[m]+EMBOFF, B: fresh hB)
        f32x16 pacc = __builtin_amdgcn_mfma_f32_32x32x16_f16(
            *(const f16x8*)(lds + wa[0] + EMBOFF), hB[0], zz, 0, 0, 0);
        #pragma unroll
        for (int m = 1; m < 4; ++m)
            pacc = __builtin_amdgcn_mfma_f32_32x32x16_f16(
                *(const f16x8*)(lds + wa[m] + EMBOFF), hB[m], pacc, 0, 0, 0);

        // C rows 0,1 (pred dims) live in hi=0 lanes, regs r=0,1; col = batch cl
        if (hi == 0) {
            float2 o2;
            o2.x = pacc[0] + b0;
            o2.y = pacc[1] + b1;
            *(float2*)(outp + t * 2) = o2;
        }
    }
}

extern "C" void kernel_launch(void* const* d_in, const int* in_sizes, int n_in,
                              void* d_out, int out_size, void* d_ws, size_t ws_size,
                              hipStream_t stream) {
    const float* xin   = (const float*)d_in[0];
    const float* Wih_e = (const float*)d_in[1];
    const float* Whh_e = (const float*)d_in[2];
    const float* bih_e = (const float*)d_in[3];
    const float* bhh_e = (const float*)d_in[4];
    const float* Wih_d = (const float*)d_in[5];
    const float* Whh_d = (const float*)d_in[6];
    const float* bih_d = (const float*)d_in[7];
    const float* bhh_d = (const float*)d_in[8];
    const float* Wemb  = (const float*)d_in[9];
    const float* bemb  = (const float*)d_in[10];
    float* outp = (float*)d_out;

    int B = in_sizes[0] / (ENC_T * 2);
    int nwg = (B + 127) / 128;
    lstm_s2s_kernel<<<dim3(nwg), dim3(256), 0, stream>>>(
        xin, Wih_e, Whh_e, bih_e, bhh_e, Wih_d, Whh_d, bih_d, bhh_d, Wemb, bemb, outp, B);
}